// Round 1
// 510.060 us; speedup vs baseline: 1.1075x; 1.1075x over previous
//
#include <hip/hip_runtime.h>

// y[b,s,n] = sum_k x[b,s,k] * (wq[n,k]*scale[blk]) + bias[n]
// M = 8192, N = 4096, K = 4096, fp32 in/out.
// R4: GEMM ported to the 256^2 8-phase template (T1 XCD swizzle + T2 LDS XOR
// swizzle + T3/T4 counted vmcnt(6) + T5 setprio). cvt pass unchanged (R3).

#define M_DIM 8192
#define N_DIM 4096
#define K_DIM 4096
#define K_TILES (K_DIM / 64)

typedef short s16x8 __attribute__((ext_vector_type(8)));   // 8 bf16 in 4 VGPRs
typedef float f32x4 __attribute__((ext_vector_type(4)));

__device__ __forceinline__ unsigned short f32_to_bf16(float f) {
    unsigned int u = __float_as_uint(f);
    unsigned int r = (u + 0x7fffu + ((u >> 16) & 1u)) >> 16;   // RNE
    return (unsigned short)r;
}

__device__ __forceinline__ ushort4 pack4(float4 a) {
    ushort4 r;
    r.x = f32_to_bf16(a.x); r.y = f32_to_bf16(a.y);
    r.z = f32_to_bf16(a.z); r.w = f32_to_bf16(a.w);
    return r;
}

// ---- fused pre-pass, fully stride-1 coalesced (unchanged from R3) ----
__global__ __launch_bounds__(256) void cvt_fused_kernel(
    const float4* __restrict__ x, const float4* __restrict__ wq,
    const float* __restrict__ scales,
    ushort4* __restrict__ xo, ushort4* __restrict__ wo) {
    const int b = blockIdx.x;
    const int t = threadIdx.x;
    if (b < 16384) {
        const int base = b * 512 + t;
#pragma unroll
        for (int j = 0; j < 2; ++j) {
            const int idx = base + j * 256;
            xo[idx] = pack4(x[idx]);
        }
    } else {
        const int base = (b - 16384) * 512 + t;
#pragma unroll
        for (int j = 0; j < 2; ++j) {
            const int idx = base + j * 256;
            const float s = scales[idx >> 5];
            float4 a = wq[idx];
            a.x *= s; a.y *= s; a.z *= s; a.w *= s;
            wo[idx] = pack4(a);
        }
    }
}

// ---- async 16B global -> LDS ----
__device__ __forceinline__ void async_copy16(const void* g, void* l) {
    __builtin_amdgcn_global_load_lds(
        (const __attribute__((address_space(1))) unsigned int*)g,
        (__attribute__((address_space(3))) unsigned int*)l,
        16, 0, 0);
}

// ---- GEMM: C[M,N] = A[M,K](bf16) * B[N,K]^T(bf16) + bias ----
// 256x256 tile, BK=64, 8 waves (2M x 4N), 512 thr, 128 KiB dbuf LDS.
// 4 phases per K-tile, each: {stage 1 half-tile of kt+1, vmcnt(6), barrier,
// 12 ds_read_b128, 16 MFMA under setprio}. Interleaved halves:
//   A-I0 = each wave's rows [0,64)   (tile rows 0-63 & 128-191)
//   A-I1 = each wave's rows [64,128) (tile rows 64-127 & 192-255)
//   B-I0 = each wave's cols [0,32), B-I1 = cols [32,64)
// phase p consumes exactly {A-I(p>=3), B-I(p even)}, so per-phase vmcnt(6)
// (3 half-tiles / 6 loads in flight) guarantees arrival exactly in time.
// LDS swizzle: byte ^= (row&7)<<4 on reads; staging keeps LDS dest linear and
// pre-swizzles the GLOBAL source column (rule #21: both sides, same involution).

#define STAGE_A_HALF(h, ktt, bufb) do {                                        \
    const unsigned short* g_ = gA0 + (ktt) * 64 + (h) * (64 * K_DIM);          \
    async_copy16(g_,               ldsA + (bufb) + (h) * 8192 + aOff);         \
    async_copy16(g_ + 128 * K_DIM, ldsA + (bufb) + (h) * 8192 + 16384 + aOff); \
  } while (0)

#define STAGE_B_HALF(h, ktt, bufb) do {                                        \
    const unsigned short* g_ = gB0 + (ktt) * 64 + (h) * (32 * K_DIM);          \
    async_copy16(g_,               ldsB + (bufb) + (h) * 4096 + bOff);         \
    async_copy16(g_ + 128 * K_DIM, ldsB + (bufb) + (h) * 4096 + 16384 + bOff); \
  } while (0)

#define PHASE(qm, qn, bufb, STAGE_STMT, WAITN) do {                            \
    STAGE_STMT;                                                                \
    asm volatile("s_waitcnt vmcnt(" #WAITN ")" ::: "memory");                  \
    __builtin_amdgcn_s_barrier();                                              \
    asm volatile("" ::: "memory");                                             \
    __builtin_amdgcn_sched_barrier(0);                                         \
    s16x8 af[4][2], bf[2][2];                                                  \
    _Pragma("unroll")                                                          \
    for (int i = 0; i < 4; ++i) {                                              \
      af[i][0] = *(const s16x8*)(ldsA + (bufb) + aRowB + ((qm)*64 + i*16)*128 + kk0); \
      af[i][1] = *(const s16x8*)(ldsA + (bufb) + aRowB + ((qm)*64 + i*16)*128 + kk1); \
    }                                                                          \
    _Pragma("unroll")                                                          \
    for (int j = 0; j < 2; ++j) {                                              \
      bf[j][0] = *(const s16x8*)(ldsB + (bufb) + bRowB + ((qn)*32 + j*16)*128 + kk0); \
      bf[j][1] = *(const s16x8*)(ldsB + (bufb) + bRowB + ((qn)*32 + j*16)*128 + kk1); \
    }                                                                          \
    __builtin_amdgcn_s_setprio(1);                                             \
    _Pragma("unroll")                                                          \
    for (int i = 0; i < 4; ++i)                                                \
      _Pragma("unroll")                                                        \
      for (int j = 0; j < 2; ++j) {                                            \
        acc[(qm)*4+i][(qn)*2+j] = __builtin_amdgcn_mfma_f32_16x16x32_bf16(     \
            af[i][0], bf[j][0], acc[(qm)*4+i][(qn)*2+j], 0, 0, 0);             \
        acc[(qm)*4+i][(qn)*2+j] = __builtin_amdgcn_mfma_f32_16x16x32_bf16(     \
            af[i][1], bf[j][1], acc[(qm)*4+i][(qn)*2+j], 0, 0, 0);             \
      }                                                                        \
    __builtin_amdgcn_s_setprio(0);                                             \
  } while (0)

__global__ __launch_bounds__(512, 2) void gemm_bt_kernel(
    const unsigned short* __restrict__ A,   // M x K bf16 bits
    const unsigned short* __restrict__ B,   // N x K bf16 bits
    const float* __restrict__ bias,         // N
    float* __restrict__ C)                  // M x N
{
    // [buf0: A 32KB | B 32KB][buf1: A 32KB | B 32KB] = 128 KiB
    __shared__ __align__(16) char lds[131072];
    char* ldsA = lds;
    char* ldsB = lds + 32768;

    const int t = threadIdx.x;
    const int l = t & 63;
    const int w = t >> 6;
    const int wr = w >> 2;          // 0..1 : wave row (128 rows each)
    const int wc = w & 3;           // 0..3 : wave col (64 cols each)

    int id = blockIdx.x;
    id = (id & 7) * 64 + (id >> 3);            // XCD-contiguous, bijective (512%8==0)
    const int m0 = (id >> 4) * 256;            // 32 m-tiles
    const int n0 = (id & 15) * 256;            // 16 n-tiles

    // ---- staging addresses (pre-swizzled global source, linear LDS dest) ----
    const int trow = t >> 3;                                // 0..63
    const int tcol = ((t & 7) * 8) ^ ((trow & 7) * 8);      // swizzled col (elems)
    const unsigned short* gA0 = A + (long)(m0 + trow) * K_DIM + tcol;
    const int brow = ((t >> 8) * 64) + ((t & 255) >> 3);    // 0..31 / 64..95 ; brow&7==trow&7
    const unsigned short* gB0 = B + (long)(n0 + brow) * K_DIM + tcol;
    const int aOff = t * 16;
    const int bOff = ((t >> 8) * 8192) + ((t & 255) * 16);

    // ---- ds_read fragment addressing (row = base+(l&15), k = ks*32+(l>>4)*8) ----
    const int aRowB = (wr * 128 + (l & 15)) * 128;   // bytes
    const int bRowB = (wc * 64  + (l & 15)) * 128;
    const int kx  = (l >> 4) * 16;
    const int sw  = (l & 7) * 16;                    // (row&7)<<4 == lane-constant
    const int kk0 = kx ^ sw;
    const int kk1 = (64 + kx) ^ sw;

    f32x4 acc[8][4] = {};

    // prologue: K-tile 0 into buf0, issue order A0,B0,B1,A1 (oldest first)
    STAGE_A_HALF(0, 0, 0);
    STAGE_B_HALF(0, 0, 0);
    STAGE_B_HALF(1, 0, 0);
    STAGE_A_HALF(1, 0, 0);

    for (int kt = 0; kt < K_TILES - 1; ++kt) {
        const int cb = (kt & 1) * 65536;
        const int nb = 65536 - cb;
        PHASE(0, 0, cb, STAGE_A_HALF(0, kt + 1, nb), 6);
        PHASE(0, 1, cb, STAGE_B_HALF(0, kt + 1, nb), 6);
        PHASE(1, 0, cb, STAGE_B_HALF(1, kt + 1, nb), 6);
        PHASE(1, 1, cb, STAGE_A_HALF(1, kt + 1, nb), 6);
    }
    {   // last K-tile: no staging; drain 4 -> 2 -> 0
        const int cb = ((K_TILES - 1) & 1) * 65536;
        PHASE(0, 0, cb, (void)0, 4);
        PHASE(0, 1, cb, (void)0, 2);
        PHASE(1, 0, cb, (void)0, 0);
        PHASE(1, 1, cb, (void)0, 0);
    }

    // epilogue: C/D layout row=(l>>4)*4+reg, col=l&15 (measured m89/m91)
    const int q4 = (l >> 4) * 4;
#pragma unroll
    for (int nf = 0; nf < 4; ++nf) {
        const int col = n0 + wc * 64 + nf * 16 + (l & 15);
        const float bv = bias[col];
#pragma unroll
        for (int mf = 0; mf < 8; ++mf) {
            const long row = m0 + wr * 128 + mf * 16 + q4;
#pragma unroll
            for (int r = 0; r < 4; ++r) {
                C[(row + r) * N_DIM + col] = acc[mf][nf][r] + bv;
            }
        }
    }
}

extern "C" void kernel_launch(void* const* d_in, const int* in_sizes, int n_in,
                              void* d_out, int out_size, void* d_ws, size_t ws_size,
                              hipStream_t stream) {
    const float* x      = (const float*)d_in[0];
    const float* wq     = (const float*)d_in[1];
    const float* scales = (const float*)d_in[2];
    const float* bias   = (const float*)d_in[3];
    float* out = (float*)d_out;

    unsigned short* x_bf = (unsigned short*)d_ws;                 // 67.1 MB
    unsigned short* w_bf = x_bf + (size_t)M_DIM * K_DIM;          // 33.6 MB

    cvt_fused_kernel<<<24576, 256, 0, stream>>>(
        (const float4*)x, (const float4*)wq, scales,
        (ushort4*)x_bf, (ushort4*)w_bf);

    gemm_bt_kernel<<<dim3(512), dim3(512), 0, stream>>>(x_bf, w_bf, bias, out);
}

// Round 2
// 497.727 us; speedup vs baseline: 1.1350x; 1.0248x over previous
//
#include <hip/hip_runtime.h>

// y[b,s,n] = sum_k x[b,s,k] * (wq[n,k]*scale[blk]) + bias[n]
// M = 8192, N = 4096, K = 4096, fp32 in/out.
// R5: GEMM -> 2-phase/K-tile schedule: 32 MFMA per barrier interval, each LDS
// fragment read ONCE per K-tile (24 ds_read_b128 vs 48), barriers halved.
// Frag regs 64 + acc 128 + addr ~= 225 (stays under the 256-reg 2-waves/SIMD
// cliff; full double-buffer at 276 would halve occupancy).
// cvt: grid-stride 2048 blocks, 16B ushort8 stores (was 24576 blocks / 8B).

#define M_DIM 8192
#define N_DIM 4096
#define K_DIM 4096
#define K_TILES (K_DIM / 64)

typedef short s16x8 __attribute__((ext_vector_type(8)));   // 8 bf16 in 4 VGPRs
typedef float f32x4 __attribute__((ext_vector_type(4)));
typedef unsigned int u32x4 __attribute__((ext_vector_type(4)));

__device__ __forceinline__ unsigned int pack2_bf16(float a, float b) {
    unsigned int ua = __float_as_uint(a);
    unsigned int ub = __float_as_uint(b);
    unsigned int ra = ((ua + 0x7fffu + ((ua >> 16) & 1u)) >> 16) & 0xffffu;  // RNE
    unsigned int rb = (ub + 0x7fffu + ((ub >> 16) & 1u)) & 0xffff0000u;
    return ra | rb;
}

// ---- fused pre-pass: grid-stride, 2 float4 loads -> 1 ushort8 (16B) store ----
// unit u = 8 consecutive floats. x units [0,NX), w units [NX,NTOT).
// NX/stride = 8 exactly -> branch is iteration-uniform (no divergence).
__global__ __launch_bounds__(256) void cvt_fused_kernel(
    const float4* __restrict__ x, const float4* __restrict__ wq,
    const float* __restrict__ scales,
    u32x4* __restrict__ xo, u32x4* __restrict__ wo) {
    const int NX   = (M_DIM * K_DIM) / 8;               // 4194304
    const int NTOT = NX + (N_DIM * K_DIM) / 8;          // 6291456
    const int stride = gridDim.x * blockDim.x;          // 524288 -> 12 iters
    for (int u = blockIdx.x * blockDim.x + threadIdx.x; u < NTOT; u += stride) {
        if (u < NX) {
            const float4 a = x[2 * u];
            const float4 b = x[2 * u + 1];
            u32x4 r;
            r[0] = pack2_bf16(a.x, a.y); r[1] = pack2_bf16(a.z, a.w);
            r[2] = pack2_bf16(b.x, b.y); r[3] = pack2_bf16(b.z, b.w);
            xo[u] = r;
        } else {
            const int v = u - NX;
            const float s = scales[v >> 4];             // 16 units per 128-block
            float4 a = wq[2 * v];
            float4 b = wq[2 * v + 1];
            a.x *= s; a.y *= s; a.z *= s; a.w *= s;
            b.x *= s; b.y *= s; b.z *= s; b.w *= s;
            u32x4 r;
            r[0] = pack2_bf16(a.x, a.y); r[1] = pack2_bf16(a.z, a.w);
            r[2] = pack2_bf16(b.x, b.y); r[3] = pack2_bf16(b.z, b.w);
            wo[v] = r;
        }
    }
}

// ---- async 16B global -> LDS ----
__device__ __forceinline__ void async_copy16(const void* g, void* l) {
    __builtin_amdgcn_global_load_lds(
        (const __attribute__((address_space(1))) unsigned int*)g,
        (__attribute__((address_space(3))) unsigned int*)l,
        16, 0, 0);
}

// ---- GEMM: C[M,N] = A[M,K](bf16) * B[N,K]^T(bf16) + bias ----
// 256x256 tile, BK=64, 8 waves (2M x 4N), 512 thr, 128 KiB dbuf LDS.
// 2 phases per K-tile:
//   ph1: stage {A0,B0}(kt+1); vmcnt(4); barrier; read af<-A0, bfX<-B0,
//        bfY<-B1 (16 ds_read_b128); 32 MFMA (C-quadrants qm=0).
//   ph2: stage {B1,A1}(kt+1); barrier; read af<-A1 (8 reads, bfX/bfY kept
//        in regs); 32 MFMA (qm=1).
// vmcnt(4) at ph1 leaves exactly {A0,B0}(kt+1) in flight and drains everything
// kt needs (incl. B1,A1 staged in ph2 of kt-1) -- each stage gets >=1 full
// phase (~600+ cyc) of flight. Never drains to 0 in the main loop.
// LDS swizzle: byte ^= (row&7)<<4 on reads; staging keeps LDS dest linear and
// pre-swizzles the GLOBAL source column (both sides, same involution).

#define STAGE_A_HALF(h, ktt, bufb) do {                                        \
    const unsigned short* g_ = gA0 + (ktt) * 64 + (h) * (64 * K_DIM);          \
    async_copy16(g_,               ldsA + (bufb) + (h) * 8192 + aOff);         \
    async_copy16(g_ + 128 * K_DIM, ldsA + (bufb) + (h) * 8192 + 16384 + aOff); \
  } while (0)

#define STAGE_B_HALF(h, ktt, bufb) do {                                        \
    const unsigned short* g_ = gB0 + (ktt) * 64 + (h) * (32 * K_DIM);          \
    async_copy16(g_,               ldsB + (bufb) + (h) * 4096 + bOff);         \
    async_copy16(g_ + 128 * K_DIM, ldsB + (bufb) + (h) * 4096 + 16384 + bOff); \
  } while (0)

#define READ_AF(dst, qm, bufb) do {                                            \
    _Pragma("unroll")                                                          \
    for (int i_ = 0; i_ < 4; ++i_) {                                           \
      dst[i_][0] = *(const s16x8*)(ldsA + (bufb) + aRowB + ((qm)*64 + i_*16)*128 + kk0); \
      dst[i_][1] = *(const s16x8*)(ldsA + (bufb) + aRowB + ((qm)*64 + i_*16)*128 + kk1); \
    }                                                                          \
  } while (0)

#define READ_BF(dst, qn, bufb) do {                                            \
    _Pragma("unroll")                                                          \
    for (int j_ = 0; j_ < 2; ++j_) {                                           \
      dst[j_][0] = *(const s16x8*)(ldsB + (bufb) + bRowB + ((qn)*32 + j_*16)*128 + kk0); \
      dst[j_][1] = *(const s16x8*)(ldsB + (bufb) + bRowB + ((qn)*32 + j_*16)*128 + kk1); \
    }                                                                          \
  } while (0)

// 32 MFMAs for C-quadrant row qm: cols 0,1 from bfX (qn=0), cols 2,3 from bfY.
// Per-accumulator k-order (ks0 then ks1, kt ascending) identical to R4 ->
// bitwise-identical output.
#define MFMA32(qm, AF, BX, BY) do {                                            \
    __builtin_amdgcn_s_setprio(1);                                             \
    _Pragma("unroll")                                                          \
    for (int i_ = 0; i_ < 4; ++i_) {                                           \
      _Pragma("unroll")                                                        \
      for (int j_ = 0; j_ < 2; ++j_) {                                         \
        acc[(qm)*4+i_][j_] = __builtin_amdgcn_mfma_f32_16x16x32_bf16(          \
            AF[i_][0], BX[j_][0], acc[(qm)*4+i_][j_], 0, 0, 0);                \
        acc[(qm)*4+i_][j_] = __builtin_amdgcn_mfma_f32_16x16x32_bf16(          \
            AF[i_][1], BX[j_][1], acc[(qm)*4+i_][j_], 0, 0, 0);                \
      }                                                                        \
      _Pragma("unroll")                                                        \
      for (int j_ = 0; j_ < 2; ++j_) {                                         \
        acc[(qm)*4+i_][2+j_] = __builtin_amdgcn_mfma_f32_16x16x32_bf16(        \
            AF[i_][0], BY[j_][0], acc[(qm)*4+i_][2+j_], 0, 0, 0);              \
        acc[(qm)*4+i_][2+j_] = __builtin_amdgcn_mfma_f32_16x16x32_bf16(        \
            AF[i_][1], BY[j_][1], acc[(qm)*4+i_][2+j_], 0, 0, 0);              \
      }                                                                        \
    }                                                                          \
    __builtin_amdgcn_s_setprio(0);                                             \
  } while (0)

__global__ __launch_bounds__(512, 2) void gemm_bt_kernel(
    const unsigned short* __restrict__ A,   // M x K bf16 bits
    const unsigned short* __restrict__ B,   // N x K bf16 bits
    const float* __restrict__ bias,         // N
    float* __restrict__ C)                  // M x N
{
    // [buf0: A 32KB | B 32KB][buf1: A 32KB | B 32KB] = 128 KiB
    __shared__ __align__(16) char lds[131072];
    char* ldsA = lds;
    char* ldsB = lds + 32768;

    const int t = threadIdx.x;
    const int l = t & 63;
    const int w = t >> 6;
    const int wr = w >> 2;          // 0..1 : wave row (128 rows each)
    const int wc = w & 3;           // 0..3 : wave col (64 cols each)

    int id = blockIdx.x;
    id = (id & 7) * 64 + (id >> 3);            // XCD-contiguous, bijective (512%8==0)
    const int m0 = (id >> 4) * 256;            // 32 m-tiles
    const int n0 = (id & 15) * 256;            // 16 n-tiles

    // ---- staging addresses (pre-swizzled global source, linear LDS dest) ----
    const int trow = t >> 3;                                // 0..63
    const int tcol = ((t & 7) * 8) ^ ((trow & 7) * 8);      // swizzled col (elems)
    const unsigned short* gA0 = A + (long)(m0 + trow) * K_DIM + tcol;
    const int brow = ((t >> 8) * 64) + ((t & 255) >> 3);    // brow&7 == trow&7
    const unsigned short* gB0 = B + (long)(n0 + brow) * K_DIM + tcol;
    const int aOff = t * 16;
    const int bOff = ((t >> 8) * 8192) + ((t & 255) * 16);

    // ---- ds_read fragment addressing (row = base+(l&15), k = ks*32+(l>>4)*8) ----
    const int aRowB = (wr * 128 + (l & 15)) * 128;   // bytes
    const int bRowB = (wc * 64  + (l & 15)) * 128;
    const int kx  = (l >> 4) * 16;
    const int sw  = (l & 7) * 16;                    // (row&7)<<4, lane-constant
    const int kk0 = kx ^ sw;
    const int kk1 = (64 + kx) ^ sw;

    f32x4 acc[8][4] = {};
    s16x8 af[4][2], bfX[2][2], bfY[2][2];

    // prologue: K-tile 0 into buf0 (8 loads; ph1's vmcnt(4) waits them)
    STAGE_A_HALF(0, 0, 0);
    STAGE_B_HALF(0, 0, 0);
    STAGE_B_HALF(1, 0, 0);
    STAGE_A_HALF(1, 0, 0);

    for (int kt = 0; kt < K_TILES - 1; ++kt) {
        const int cb = (kt & 1) * 65536;
        const int nb = 65536 - cb;
        // ---- phase 1 ----
        STAGE_A_HALF(0, kt + 1, nb);
        STAGE_B_HALF(0, kt + 1, nb);
        asm volatile("s_waitcnt vmcnt(4)" ::: "memory");
        __builtin_amdgcn_s_barrier();
        __builtin_amdgcn_sched_barrier(0);
        READ_AF(af, 0, cb);
        READ_BF(bfX, 0, cb);
        READ_BF(bfY, 1, cb);
        MFMA32(0, af, bfX, bfY);
        // ---- phase 2 ----
        STAGE_B_HALF(1, kt + 1, nb);
        STAGE_A_HALF(1, kt + 1, nb);
        __builtin_amdgcn_s_barrier();
        __builtin_amdgcn_sched_barrier(0);
        READ_AF(af, 1, cb);
        MFMA32(1, af, bfX, bfY);
    }
    {   // last K-tile: drain (vmcnt(0) allowed outside main loop)
        const int cb = ((K_TILES - 1) & 1) * 65536;
        asm volatile("s_waitcnt vmcnt(0)" ::: "memory");
        __builtin_amdgcn_s_barrier();
        __builtin_amdgcn_sched_barrier(0);
        READ_AF(af, 0, cb);
        READ_BF(bfX, 0, cb);
        READ_BF(bfY, 1, cb);
        MFMA32(0, af, bfX, bfY);
        __builtin_amdgcn_s_barrier();
        __builtin_amdgcn_sched_barrier(0);
        READ_AF(af, 1, cb);
        MFMA32(1, af, bfX, bfY);
    }

    // epilogue: C/D layout row=(l>>4)*4+reg, col=l&15 (measured m89/m91)
    const int q4 = (l >> 4) * 4;
#pragma unroll
    for (int nf = 0; nf < 4; ++nf) {
        const int col = n0 + wc * 64 + nf * 16 + (l & 15);
        const float bv = bias[col];
#pragma unroll
        for (int mf = 0; mf < 8; ++mf) {
            const long row = m0 + wr * 128 + mf * 16 + q4;
#pragma unroll
            for (int r = 0; r < 4; ++r) {
                C[(row + r) * N_DIM + col] = acc[mf][nf][r] + bv;
            }
        }
    }
}

extern "C" void kernel_launch(void* const* d_in, const int* in_sizes, int n_in,
                              void* d_out, int out_size, void* d_ws, size_t ws_size,
                              hipStream_t stream) {
    const float* x      = (const float*)d_in[0];
    const float* wq     = (const float*)d_in[1];
    const float* scales = (const float*)d_in[2];
    const float* bias   = (const float*)d_in[3];
    float* out = (float*)d_out;

    unsigned short* x_bf = (unsigned short*)d_ws;                 // 67.1 MB
    unsigned short* w_bf = x_bf + (size_t)M_DIM * K_DIM;          // 33.6 MB

    cvt_fused_kernel<<<2048, 256, 0, stream>>>(
        (const float4*)x, (const float4*)wq, scales,
        (u32x4*)x_bf, (u32x4*)w_bf);

    gemm_bt_kernel<<<dim3(512), dim3(512), 0, stream>>>(x_bf, w_bf, bias, out);
}